// Round 1
// 638.966 us; speedup vs baseline: 1.0448x; 1.0448x over previous
//
#include <hip/hip_runtime.h>
#include <hip/hip_bf16.h>

// TT layer via MFMA bf16:
// out[n,a,b,c,d] = relu( sum x[n,ijkl] G1[a,i,r] G2[b,j,r,s] G3[c,k,s,t] G4[d,l,t] + bias[abcd] )
//
// prep:   one block converts G1..G4 fp32->bf16 into the exact padded LDS image
//         layouts (zero K-pad included) in d_ws; passes stage them as uint4 copies.
// Pass A (block = n, k-pair): stage1: T1[(j,l),(a,r)] = x^T G1 (K=16 zero-padded to 32)
//                             stage2: T2[(a,l),(b,s)] = T1 G2  (K=64)
//                             -> T2 global [n'][a][k*16+l][b*4+s] bf16 (d_ws)
//         k-pair loop: the two k-slices share 128B lines -> no half-line overfetch,
//         and G-image staging/zero-fill is amortized over 2 slices.
// Pass B (block = n, a):      stage3: T3[(b,l),(c,t)] = T2 G3  (K=64)
//                             stage4: out[(b,c),d]    = T3 G4  (K=64) + bias, relu
//
// 512-thread blocks (8 waves, each owns 2 row-tiles instead of 4): same LDS tile,
// 2 blocks/CU -> 16 waves/CU (was 8) to hide LDS->MFMA dependency latency.
//
// MFMA 16x16x32 bf16 layouts (gfx950, HW-verified per guide):
//   A frag: lane holds A[m=ln][k=quad*8+j]; B frag: B[k=quad*8+j][n=ln]
//   C/D: col=ln, row=quad*4+reg. Swapped mfma(B,A) = C^T -> regs span the N index,
//   so inter-stage repack is a packed ds_write_b64.

typedef __attribute__((ext_vector_type(8))) short bf16x8;
typedef __attribute__((ext_vector_type(4))) float f32x4;
typedef unsigned short u16;
typedef unsigned long long u64;

#define T2_PER_N 262144           // 16(a) * 256(kl) * 64(b*4+s) bf16 elems
#define PAD40 40                  // 16 real K + 16 zeros + 8 pad (stage-1 rows)
#define PAD72 72                  // 64 K + 8 pad (144B rows, 16B aligned, 2-way)

// G-core image layout in d_ws (u16 offsets):
//   imgA: g1s [64][PAD40] @ 0      (2560 u16)
//         g2s [64][PAD72] @ 2560   (4608 u16)   -> 7168 u16 = 896 uint4
//   imgB: g3s [64][PAD72] @ 7168   (4608 u16)
//         g4s [16][PAD72] @ 11776  (1152 u16)   -> 5760 u16 = 720 uint4
//   T2 region starts at u16 offset 16384 (32 KB).

static __device__ __forceinline__ u16 f2bf(float f) {
  __hip_bfloat16 h = __float2bfloat16(f);
  return *reinterpret_cast<u16*>(&h);
}
static __device__ __forceinline__ u64 pack4(f32x4 a) {
  union { u16 s[4]; u64 u; } p;
  p.s[0] = f2bf(a[0]); p.s[1] = f2bf(a[1]); p.s[2] = f2bf(a[2]); p.s[3] = f2bf(a[3]);
  return p.u;
}
#define MFMA(A, B, C) __builtin_amdgcn_mfma_f32_16x16x32_bf16((A), (B), (C), 0, 0, 0)

__global__ void tt_prep(const float* __restrict__ G1, const float* __restrict__ G2,
                        const float* __restrict__ G3, const float* __restrict__ G4,
                        u16* __restrict__ img)
{
  const int tid = threadIdx.x;
  const uint4 z = {0, 0, 0, 0};
  for (int idx = tid; idx < 1616; idx += 256) ((uint4*)img)[idx] = z;  // 12928 u16
  __syncthreads();
  #pragma unroll
  for (int it = 0; it < 4; ++it) {   // G1[a,i,r] -> g1s[(a*4+r)][i]
    const int e = it * 256 + tid, a = e >> 6, i = (e >> 2) & 15, r = e & 3;
    img[(a * 4 + r) * PAD40 + i] = f2bf(G1[e]);
  }
  #pragma unroll
  for (int it = 0; it < 16; ++it) {  // G2[b,j,r,s] -> g2s[(b*4+s)][j*4+r]
    const int e = it * 256 + tid, b = e >> 8, j = (e >> 4) & 15, r = (e >> 2) & 3, s = e & 3;
    img[2560 + (b * 4 + s) * PAD72 + j * 4 + r] = f2bf(G2[e]);
  }
  #pragma unroll
  for (int it = 0; it < 16; ++it) {  // G3[c,k,s,t] -> g3s[(c*4+t)][k*4+s]
    const int e = it * 256 + tid, c = e >> 8, k = (e >> 4) & 15, s = (e >> 2) & 3, t = e & 3;
    img[7168 + (c * 4 + t) * PAD72 + k * 4 + s] = f2bf(G3[e]);
  }
  #pragma unroll
  for (int it = 0; it < 4; ++it) {   // G4[d,l,t] -> g4s[d][t*16+l]
    const int e = it * 256 + tid, d = e >> 6, l = (e >> 2) & 15, t = e & 3;
    img[11776 + d * PAD72 + t * 16 + l] = f2bf(G4[e]);
  }
}

__global__ __launch_bounds__(512, 4) void tt_passA(
    const float* __restrict__ x, const u16* __restrict__ img,
    u16* __restrict__ T2, int n0)
{
  const int tid = threadIdx.x;
  const int kp   = blockIdx.x;          // k-pair: handles k = 2*kp, 2*kp+1
  const int slot = blockIdx.y;
  const int n = n0 + slot;
  const int lane = tid & 63, w = tid >> 6, quad = (lane >> 4) & 3, ln = lane & 15;

  __shared__ __align__(16) u16 gAs[7168];         // g1s @0 [64][40], g2s @2560 [64][72]
  __shared__ __align__(16) u16 xs [256 * PAD40];  // A1: [m1=j*16+l][i 0..15, zeros 16..31]
  __shared__ __align__(16) u16 t1s[256 * PAD72];  // A2: [m2=a*16+l][k2=j*4+r]; reused as T2 staging

  // ---- staging: G images are pure vector copies (pre-converted by tt_prep) ----
  for (int idx = tid; idx < 896; idx += 512)
    ((uint4*)gAs)[idx] = ((const uint4*)img)[idx];
  {  // zero the padded K half (cols 16..31) of xs, once for both k-slices
    const uint4 z = {0, 0, 0, 0};
    const int row = tid >> 1, h = tid & 1;
    *(uint4*)&xs[row * PAD40 + 16 + h * 8] = z;
  }

  const float4* xg = (const float4*)x + (size_t)n * 16384;
  uint4* Tg = (uint4*)(T2 + (size_t)slot * T2_PER_N);

  #pragma unroll
  for (int kx = 0; kx < 2; ++kx) {
    const int k = kp * 2 + kx;
    // ---- x[i,j,k,l] -> xs[j*16+l][i]; second kx re-hits the same 128B lines in L1 ----
    #pragma unroll
    for (int it = 0; it < 2; ++it) {
      const int e = it * 512 + tid, i = (e >> 2) & 15, j = e >> 6, lq = e & 3;
      const float4 v = xg[i * 1024 + j * 64 + k * 4 + lq];
      xs[(j * 16 + lq * 4 + 0) * PAD40 + i] = f2bf(v.x);
      xs[(j * 16 + lq * 4 + 1) * PAD40 + i] = f2bf(v.y);
      xs[(j * 16 + lq * 4 + 2) * PAD40 + i] = f2bf(v.z);
      xs[(j * 16 + lq * 4 + 3) * PAD40 + i] = f2bf(v.w);
    }
    __syncthreads();  // xs ready; also fences gAs copy (kx=0) and T2-store t1s reads (kx=1)

    // ---- stage 1 (swapped: regs span n1=(a,r) so t1s write packs along k2=j*4+r) ----
    {
      bf16x8 a1[2];
      #pragma unroll
      for (int t = 0; t < 2; ++t)
        a1[t] = *(const bf16x8*)&xs[((w * 2 + t) * 16 + ln) * PAD40 + quad * 8];
      #pragma unroll
      for (int tn = 0; tn < 4; ++tn) {
        const bf16x8 b1 = *(const bf16x8*)&gAs[(tn * 16 + ln) * PAD40 + quad * 8];
        #pragma unroll
        for (int t = 0; t < 2; ++t) {
          f32x4 acc = {0.f, 0.f, 0.f, 0.f};
          acc = MFMA(b1, a1[t], acc);     // swapped: row=n1_local, col=m1_local
          // elem (j=w*2+t, l=ln, a=tn*4+quad, r=reg) -> t1s[a*16+l][j*4+r]
          *(u64*)&t1s[((tn * 4 + quad) * 16 + ln) * PAD72 + (w * 2 + t) * 4] = pack4(acc);
        }
      }
    }
    __syncthreads();

    // ---- stage 2 (swapped: regs span n2=(b,s) -> T2 staging rows pack along bs) ----
    {
      bf16x8 a2[2][2];
      #pragma unroll
      for (int t = 0; t < 2; ++t)
        #pragma unroll
        for (int ks = 0; ks < 2; ++ks)
          a2[t][ks] = *(const bf16x8*)&t1s[((w * 2 + t) * 16 + ln) * PAD72 + ks * 32 + quad * 8];
      __syncthreads();  // all t1s frag reads done before overlaying it as T2 staging
      const u16* g2s = gAs + 2560;
      #pragma unroll
      for (int tn = 0; tn < 4; ++tn) {
        const bf16x8 b20 = *(const bf16x8*)&g2s[(tn * 16 + ln) * PAD72 + quad * 8];
        const bf16x8 b21 = *(const bf16x8*)&g2s[(tn * 16 + ln) * PAD72 + 32 + quad * 8];
        #pragma unroll
        for (int t = 0; t < 2; ++t) {
          f32x4 acc = {0.f, 0.f, 0.f, 0.f};
          acc = MFMA(b20, a2[t][0], acc);
          acc = MFMA(b21, a2[t][1], acc);
          // elem (a=w*2+t, l=ln, bs=tn*16+quad*4+reg) -> staging row a*16+l
          *(u64*)&t1s[((w * 2 + t) * 16 + ln) * PAD72 + tn * 16 + quad * 4] = pack4(acc);
        }
      }
    }
    __syncthreads();

    // ---- coalesced store: staging row (a*16+l) of 64 bf16 -> T2[a][k*16+l][bs] ----
    #pragma unroll
    for (int it = 0; it < 4; ++it) {
      const int e = it * 512 + tid, row = e >> 3, seg = e & 7;
      const uint4 q = *(const uint4*)&t1s[row * PAD72 + seg * 8];
      Tg[(row >> 4) * 2048 + k * 128 + (row & 15) * 8 + seg] = q;
    }
    // next iteration's first __syncthreads (after x staging) fences these t1s reads
  }
}

__global__ __launch_bounds__(512, 4) void tt_passB(
    const u16* __restrict__ T2, const u16* __restrict__ img,
    const float* __restrict__ bias, float* __restrict__ out, int n0)
{
  const int tid = threadIdx.x;
  const int a    = blockIdx.x;
  const int slot = blockIdx.y;
  const int n = n0 + slot;
  const int lane = tid & 63, w = tid >> 6, quad = (lane >> 4) & 3, ln = lane & 15;

  __shared__ __align__(16) u16 gBs[5760];         // g3s @0 [64][72], g4s @4608 [16][72]
  __shared__ __align__(16) u16 t2a[256 * PAD72];  // A3: [m3=b*16+l][k3=k*4+s]; reused as A4

  // ---- staging ----
  for (int idx = tid; idx < 720; idx += 512)
    ((uint4*)gBs)[idx] = ((const uint4*)(img + 7168))[idx];
  {  // T2[a][k*16+l][bs] (coalesced uint4) -> t2a[b*16+l][k*4+s] (b64 per 4-s group)
    const uint4* Tg = (const uint4*)(T2 + (size_t)slot * T2_PER_N) + a * 2048;
    #pragma unroll
    for (int it = 0; it < 4; ++it) {
      const int e = it * 512 + tid, kl = e >> 3, bq = e & 7;
      const uint4 q = Tg[e];
      const int k = kl >> 4, l = kl & 15, b0 = bq * 2;
      const u64 lo = ((u64)q.y << 32) | q.x, hi = ((u64)q.w << 32) | q.z;
      *(u64*)&t2a[(b0 * 16 + l) * PAD72 + k * 4]       = lo;  // b = b0,   s = 0..3
      *(u64*)&t2a[((b0 + 1) * 16 + l) * PAD72 + k * 4] = hi;  // b = b0+1
    }
  }
  __syncthreads();

  // ---- stage 3 (normal: regs span m3 -> l, so t3s write packs along k4=t*16+l) ----
  {
    bf16x8 a3[2][2];
    #pragma unroll
    for (int t = 0; t < 2; ++t)
      #pragma unroll
      for (int ks = 0; ks < 2; ++ks)
        a3[t][ks] = *(const bf16x8*)&t2a[((w * 2 + t) * 16 + ln) * PAD72 + ks * 32 + quad * 8];
    __syncthreads();  // all t2a frag reads done before overlay as t3s
    #pragma unroll
    for (int tn = 0; tn < 4; ++tn) {
      const bf16x8 b30 = *(const bf16x8*)&gBs[(tn * 16 + ln) * PAD72 + quad * 8];
      const bf16x8 b31 = *(const bf16x8*)&gBs[(tn * 16 + ln) * PAD72 + 32 + quad * 8];
      #pragma unroll
      for (int t = 0; t < 2; ++t) {
        f32x4 acc = {0.f, 0.f, 0.f, 0.f};
        acc = MFMA(a3[t][0], b30, acc);  // normal: row=m3_local, col=n3_local
        acc = MFMA(a3[t][1], b31, acc);
        // elem (b=w*2+t, l=quad*4+reg, c=tn*4+(ln>>2), t3=ln&3) -> t3s[b*16+c][t3*16+l]
        *(u64*)&t2a[((w * 2 + t) * 16 + tn * 4 + (ln >> 2)) * PAD72 + (ln & 3) * 16 + quad * 4]
            = pack4(acc);
      }
    }
  }
  __syncthreads();

  // ---- stage 4 + epilogue ----
  {
    const u16* g4s = gBs + 4608;
    bf16x8 b4[2];
    #pragma unroll
    for (int ks = 0; ks < 2; ++ks)
      b4[ks] = *(const bf16x8*)&g4s[ln * PAD72 + ks * 32 + quad * 8];
    const size_t obase = (size_t)n * 65536;
    #pragma unroll
    for (int t = 0; t < 2; ++t) {
      bf16x8 a40 = *(const bf16x8*)&t2a[((w * 2 + t) * 16 + ln) * PAD72 + quad * 8];
      bf16x8 a41 = *(const bf16x8*)&t2a[((w * 2 + t) * 16 + ln) * PAD72 + 32 + quad * 8];
      f32x4 acc = {0.f, 0.f, 0.f, 0.f};
      acc = MFMA(a40, b4[0], acc);
      acc = MFMA(a41, b4[1], acc);
      #pragma unroll
      for (int r = 0; r < 4; ++r) {
        const int m4 = (w * 2 + t) * 16 + quad * 4 + r;      // b*16+c
        const int off = a * 4096 + m4 * 16 + ln;             // within-sample offset
        const float v = acc[r] + bias[off];
        out[obase + off] = fmaxf(v, 0.f);
      }
    }
  }
}

extern "C" void kernel_launch(void* const* d_in, const int* in_sizes, int n_in,
                              void* d_out, int out_size, void* d_ws, size_t ws_size,
                              hipStream_t stream) {
  const float* x    = (const float*)d_in[0];
  const float* G1   = (const float*)d_in[1];
  const float* G2   = (const float*)d_in[2];
  const float* G3   = (const float*)d_in[3];
  const float* G4   = (const float*)d_in[4];
  const float* bias = (const float*)d_in[5];
  float* out = (float*)d_out;
  u16* img = (u16*)d_ws;
  u16* T2  = (u16*)d_ws + 16384;        // T2 region at +32 KB

  const int Bn = 1024;
  const size_t per_n = (size_t)T2_PER_N * sizeof(u16);  // 512 KB
  size_t avail = (ws_size > 32768) ? (ws_size - 32768) : 0;
  int chunk = (int)(avail / per_n);
  if (chunk > 256) chunk = 256;         // keep T2 (<=128 MB) Infinity-Cache-resident
  if (chunk < 1) chunk = 1;

  tt_prep<<<1, 256, 0, stream>>>(G1, G2, G3, G4, img);
  for (int nn0 = 0; nn0 < Bn; nn0 += chunk) {
    const int c = (nn0 + chunk <= Bn) ? chunk : (Bn - nn0);
    tt_passA<<<dim3(8, c), 512, 0, stream>>>(x, img, T2, nn0);
    tt_passB<<<dim3(16, c), 512, 0, stream>>>(T2, img, bias, out, nn0);
  }
}